// Round 6
// baseline (432.597 us; speedup 1.0000x reference)
//
#include <hip/hip_runtime.h>

#define Bn 512
#define Cn 202
#define Pn 27
#define Nn 729
#define CHn 200
#define Kn 58
#define OUTCn 64
#define CENTERn 364    // 13*27+13
#define NCHUNK 7
#define POOLR 176      // pool rows incl. zero-pad
#define CHP 224        // padded channels
#define UROW 72        // U row stride (shorts) = 144 B
#define ZSLOT 160
#define MCAP 192
#define SPAD 864
#define TSTR 68        // epilogue transpose stride (floats); 17*16B rows -> aligned f32x4

// conv LDS layout (bytes)
#define U_BYTES (3 * POOLR * UROW * 2)     // 76,032
#define SLOT_OFF U_BYTES
#define LB_BYTES (U_BYTES + 1728)          // 77,760  -> 2 blocks/CU

typedef float f32x4 __attribute__((ext_vector_type(4)));
typedef short s16x8 __attribute__((ext_vector_type(8)));
typedef short s16x4 __attribute__((ext_vector_type(4)));

static __device__ __forceinline__ unsigned short f2bf(float f) {
  unsigned u = __float_as_uint(f);
  u += 0x7fffu + ((u >> 16) & 1u);   // RNE
  return (unsigned short)(u >> 16);
}
static __device__ __forceinline__ float bf2f(short s) {
  return __uint_as_float(((unsigned)(unsigned short)s) << 16);
}

// ---------------- Kernel A: build slot table + masked-pool list per batch ----------------
__global__ __launch_bounds__(256) void src_kernel(const float* __restrict__ x,
                                                  const int* __restrict__ rand_idx,
                                                  short* __restrict__ slotpad_ws,
                                                  short* __restrict__ Mws,
                                                  int* __restrict__ num1_ws) {
  int b = blockIdx.x;
  __shared__ float sp[Nn];
  __shared__ short slotS[Nn];
  __shared__ short M[Nn];
  __shared__ int s_num;
  int tid = threadIdx.x;
  const float* xsp = x + ((size_t)b * Cn + CHn) * Nn;
  for (int n = tid; n < Nn; n += 256) sp[n] = xsp[n];
  __syncthreads();
  float central = sp[CENTERn];
  __syncthreads();
  for (int k = tid; k < Kn; k += 256) sp[rand_idx[b * Kn + k]] = central;
  __syncthreads();
  if (tid == 0) {
    int cm = 0, cz = 0;
    for (int n = 0; n < Nn; ++n) {
      if (sp[n] == central) { M[cm] = (short)n; slotS[n] = (short)cm; cm++; }
      else { slotS[n] = (short)(~cz); cz++; }
    }
    s_num = cm;
  }
  __syncthreads();
  int num = s_num;
  int numc = num < 160 ? num : 160;
  if (tid == 0) num1_ws[b] = numc;
  for (int m = tid; m < MCAP; m += 256) Mws[(size_t)b * MCAP + m] = (m < num) ? M[m] : (short)0;
  for (int idx = tid; idx < 841; idx += 256) {
    int pi = idx / 29, pj = idx - pi * 29;
    short v = (short)ZSLOT;
    if (pi >= 1 && pi <= 27 && pj >= 1 && pj <= 27) {
      int n = (pi - 1) * Pn + (pj - 1);
      int s0 = slotS[n];
      int sv = (s0 >= 0) ? s0 : ((~s0) % num);
      if (sv > 159) sv = 159;
      v = (short)sv;
    }
    slotpad_ws[(size_t)b * SPAD + idx] = v;
  }
}

// ---------------- Kernel B: weights -> bf16, chunked layout Wt2[ck][r][o][32] ----------------
__global__ __launch_bounds__(256) void wprep_kernel(const float* __restrict__ W,
                                                    short* __restrict__ Wt2) {
  int idx = blockIdx.x * 256 + threadIdx.x;
  if (idx >= NCHUNK * 9 * OUTCn * 32) return;
  int ck = idx / (9 * OUTCn * 32);
  int rem = idx - ck * (9 * OUTCn * 32);
  int r = rem / (OUTCn * 32);
  int rem2 = rem - r * (OUTCn * 32);
  int o = rem2 >> 5;
  int cl = rem2 & 31;
  int c = ck * 32 + cl;
  float v = (c < CHn) ? W[((size_t)o * CHn + c) * 9 + r] : 0.f;
  Wt2[idx] = (short)f2bf(v);
}

// ---------------- Kernel P: coalesced pool gather via LDS scatter ----------------
// grid (14, 512): block = (16-channel chunk ck, batch b). Stage 16 planes coalesced,
// scatter-read in LDS, write Pool_ws[b][176][224] bf16 coalesced.
__global__ __launch_bounds__(512, 4) void pool_kernel(const float* __restrict__ x,
                                                      const short* __restrict__ Mws,
                                                      const int* __restrict__ num1_ws,
                                                      short* __restrict__ Pool_ws) {
  __shared__ float xs[16 * Nn];   // 46,656 B
  const int ck = blockIdx.x;      // 0..13
  const int b = blockIdx.y;
  const int tid = threadIdx.x;
  const int num1 = num1_ws[b];
  const float* xb = x + (size_t)b * Cn * Nn;

  // coalesced stage (invalid channels -> 0)
  for (int i = tid; i < 16 * Nn; i += 512) {
    int cl = i / Nn;
    int n = i - cl * Nn;
    int c = ck * 16 + cl;
    xs[i] = (c < CHn) ? xb[(size_t)c * Nn + n] : 0.f;
  }
  __syncthreads();

  // scatter-read in LDS, coalesced global write
  if (tid < POOLR * 2) {
    int m = tid >> 1;
    int cq = tid & 1;
    bool valid = m < num1;
    int s = valid ? (int)Mws[(size_t)b * MCAP + m] : 0;
    s16x8 w8;
#pragma unroll
    for (int j = 0; j < 8; ++j) {
      float v = valid ? xs[(cq * 8 + j) * Nn + s] : 0.f;
      w8[j] = (short)f2bf(v);
    }
    *(s16x8*)(Pool_ws + (size_t)b * (POOLR * CHP) + (size_t)m * CHP + ck * 16 + cq * 8) = w8;
  }
}

// ---------------- Kernel C: U = W_r x Pool (global B), gather-accumulate, transpose-store ----------------
// 512 blocks (1/batch), 1024 thr = 16 waves. LDS 77.8 KB -> 2 blocks/CU.
__global__ __launch_bounds__(1024, 4) void conv_kernel(const short* __restrict__ Wt2,
                                                       const short* __restrict__ Pool_ws,
                                                       const float* __restrict__ bias,
                                                       const short* __restrict__ slotpad_ws,
                                                       float* __restrict__ y) {
  __shared__ __align__(16) char LB[LB_BYTES];
  short* U = (short*)LB;                    // [3][176][72] bf16
  short* Slot = (short*)(LB + SLOT_OFF);    // [841]
  float* T = (float*)LB;                    // [184][68] overlay for epilogue

  const int b = blockIdx.x;
  const int tid = threadIdx.x;
  const int lane = tid & 63;
  const int wv = tid >> 6;       // 0..15
  const int l16 = lane & 15;
  const int kg = lane >> 4;      // 0..3

  if (tid < 841) Slot[tid] = slotpad_ws[(size_t)b * SPAD + tid];

  // per-thread gather geometry: wave owns pixels [46*wv, 46*wv+46); thread: sub=kg, o-quad=l16*4
  const int pbase = wv * 46;
  const int oq = l16 * 4;
  int sb[12];
  unsigned vmask = 0;
#pragma unroll
  for (int it = 0; it < 12; ++it) {
    int pl = 4 * it + kg;
    int p = pbase + pl;
    bool v = (pl < 46) && (p < Nn);
    int pc = v ? p : (Nn - 1);
    int pi = pc / Pn, pj = pc - pi * Pn;
    sb[it] = pi * 29 + pj;
    if (v) vmask |= (1u << it);
  }

  float acc[12][4];
#pragma unroll
  for (int it = 0; it < 12; ++it)
#pragma unroll
    for (int q = 0; q < 4; ++q) acc[it][q] = 0.f;

  const short* poolb = Pool_ws + (size_t)b * (POOLR * CHP);

  for (int g = 0; g < 3; ++g) {
    // ---- U-GEMM: U[rl][slot][o] = sum_c W[r=3g+rl][o][c] * Pool[slot][c]
    // A from Wt2 (global/L2), B from Pool_ws (global/L2). 132 combos over 16 waves.
    for (int c = wv; c < 132; c += 16) {
      int rl = c / 44;
      int rem = c - rl * 44;
      int ot = rem / 11;
      int nt = rem - ot * 11;
      int r = g * 3 + rl;
      const short* wp = Wt2 + ((size_t)r * 64 + ot * 16 + l16) * 32 + kg * 8;
      const short* pp = poolb + (nt * 16 + l16) * CHP + kg * 8;
      f32x4 a = (f32x4){0.f, 0.f, 0.f, 0.f};
#pragma unroll
      for (int ck = 0; ck < NCHUNK; ++ck) {
        s16x8 av = *(const s16x8*)(wp + ck * (9 * 64 * 32));
        s16x8 bv = *(const s16x8*)(pp + ck * 32);
        a = __builtin_amdgcn_mfma_f32_16x16x32_bf16(av, bv, a, 0, 0, 0);
      }
      s16x4 u4 = {(short)f2bf(a[0]), (short)f2bf(a[1]), (short)f2bf(a[2]), (short)f2bf(a[3])};
      *(s16x4*)(U + ((size_t)rl * POOLR + nt * 16 + l16) * UROW + ot * 16 + kg * 4) = u4;
    }
    __syncthreads();   // U ready (also orders Slot for g=0)

    // ---- gather-accumulate: acc[n][o] += U[dc][slot(n; dr=g, dc)][o]
#pragma unroll
    for (int it = 0; it < 12; ++it) {
#pragma unroll
      for (int rl = 0; rl < 3; ++rl) {
        int slot = Slot[sb[it] + g * 29 + rl];
        s16x4 u4 = *(const s16x4*)(U + ((size_t)rl * POOLR + slot) * UROW + oq);
        acc[it][0] += bf2f(u4[0]);
        acc[it][1] += bf2f(u4[1]);
        acc[it][2] += bf2f(u4[2]);
        acc[it][3] += bf2f(u4[3]);
      }
    }
    __syncthreads();   // gather done before next U overwrite / epilogue overlay
  }

  // ---- epilogue: 4 transpose chunks of 184 pixels through LDS, coalesced stores
  f32x4 bq = *(const f32x4*)&bias[oq];
  const int o = tid >> 4;
  const int sub = tid & 15;
#pragma unroll
  for (int cch = 0; cch < 4; ++cch) {
    if ((wv >> 2) == cch) {
#pragma unroll
      for (int it = 0; it < 12; ++it) {
        if ((vmask >> it) & 1u) {
          int p = pbase + 4 * it + kg;
          f32x4 v = {acc[it][0] + bq[0], acc[it][1] + bq[1], acc[it][2] + bq[2], acc[it][3] + bq[3]};
          *(f32x4*)&T[(p - 184 * cch) * TSTR + oq] = v;
        }
      }
    }
    __syncthreads();
    int lim = (cch == 3) ? (Nn - 552) : 184;
    float* yo = y + ((size_t)b * OUTCn + o) * Nn + 184 * cch;
#pragma unroll
    for (int it2 = 0; it2 < 12; ++it2) {
      int n = it2 * 16 + sub;
      if (n < lim) yo[n] = T[n * TSTR + o];
    }
    __syncthreads();   // T free for next chunk
  }
}

extern "C" void kernel_launch(void* const* d_in, const int* in_sizes, int n_in,
                              void* d_out, int out_size, void* d_ws, size_t ws_size,
                              hipStream_t stream) {
  const float* x = (const float*)d_in[0];
  const float* W = (const float*)d_in[1];
  const float* bias = (const float*)d_in[2];
  const int* rand_idx = (const int*)d_in[3];
  float* y = (float*)d_out;

  // workspace layout
  char* p = (char*)d_ws;
  short* slotpad = (short*)p;                 p += 884736;            // 512*864*2
  short* Mws = (short*)p;                     p += 196608;            // 512*192*2
  int* num1 = (int*)p;                        p += 2048;
  short* Wt2 = (short*)p;                     p += 258048;            // 7*9*64*32*2
  short* Pool_ws = (short*)p;                                         // 512*176*224*2 = 40,370,176 B

  src_kernel<<<Bn, 256, 0, stream>>>(x, rand_idx, slotpad, Mws, num1);
  wprep_kernel<<<(NCHUNK * 9 * OUTCn * 32 + 255) / 256, 256, 0, stream>>>(W, Wt2);
  pool_kernel<<<dim3(14, Bn), 512, 0, stream>>>(x, Mws, num1, Pool_ws);
  conv_kernel<<<Bn, 1024, 0, stream>>>(Wt2, Pool_ws, bias, slotpad, y);
}

// Round 7
// 419.939 us; speedup vs baseline: 1.0301x; 1.0301x over previous
//
#include <hip/hip_runtime.h>

#define Bn 512
#define Cn 202
#define Pn 27
#define Nn 729
#define CHn 200
#define Kn 58
#define OUTCn 64
#define CENTERn 364    // 13*27+13
#define NCHUNK 7
#define POOLR 176      // pool rows incl. zero-pad
#define CHP 224        // padded channels
#define ZSLOT 160
#define MCAP 192
#define SPAD 864

typedef float f32x4 __attribute__((ext_vector_type(4)));
typedef short s16x8 __attribute__((ext_vector_type(8)));
typedef short s16x4 __attribute__((ext_vector_type(4)));

static __device__ __forceinline__ unsigned short f2bf(float f) {
  unsigned u = __float_as_uint(f);
  u += 0x7fffu + ((u >> 16) & 1u);   // RNE
  return (unsigned short)(u >> 16);
}
static __device__ __forceinline__ float bf2f(short s) {
  return __uint_as_float(((unsigned)(unsigned short)s) << 16);
}

// ---------------- Kernel A: build slot table + masked-pool list per batch ----------------
__global__ __launch_bounds__(256) void src_kernel(const float* __restrict__ x,
                                                  const int* __restrict__ rand_idx,
                                                  short* __restrict__ slotpad_ws,
                                                  short* __restrict__ Mws,
                                                  int* __restrict__ num1_ws) {
  int b = blockIdx.x;
  __shared__ float sp[Nn];
  __shared__ short slotS[Nn];
  __shared__ short M[Nn];
  __shared__ int s_num;
  int tid = threadIdx.x;
  const float* xsp = x + ((size_t)b * Cn + CHn) * Nn;
  for (int n = tid; n < Nn; n += 256) sp[n] = xsp[n];
  __syncthreads();
  float central = sp[CENTERn];
  __syncthreads();
  for (int k = tid; k < Kn; k += 256) sp[rand_idx[b * Kn + k]] = central;
  __syncthreads();
  if (tid == 0) {
    int cm = 0, cz = 0;
    for (int n = 0; n < Nn; ++n) {
      if (sp[n] == central) { M[cm] = (short)n; slotS[n] = (short)cm; cm++; }
      else { slotS[n] = (short)(~cz); cz++; }
    }
    s_num = cm;
  }
  __syncthreads();
  int num = s_num;
  int numc = num < 160 ? num : 160;
  if (tid == 0) num1_ws[b] = numc;
  for (int m = tid; m < MCAP; m += 256) Mws[(size_t)b * MCAP + m] = (m < num) ? M[m] : (short)0;
  for (int idx = tid; idx < 841; idx += 256) {
    int pi = idx / 29, pj = idx - pi * 29;
    short v = (short)ZSLOT;
    if (pi >= 1 && pi <= 27 && pj >= 1 && pj <= 27) {
      int n = (pi - 1) * Pn + (pj - 1);
      int s0 = slotS[n];
      int sv = (s0 >= 0) ? s0 : ((~s0) % num);
      if (sv > 159) sv = 159;
      v = (short)sv;
    }
    slotpad_ws[(size_t)b * SPAD + idx] = v;
  }
}

// ---------------- Kernel B: weights -> bf16, chunked layout Wt2[ck][r][o][32] ----------------
__global__ __launch_bounds__(256) void wprep_kernel(const float* __restrict__ W,
                                                    short* __restrict__ Wt2) {
  int idx = blockIdx.x * 256 + threadIdx.x;
  if (idx >= NCHUNK * 9 * OUTCn * 32) return;
  int ck = idx / (9 * OUTCn * 32);
  int rem = idx - ck * (9 * OUTCn * 32);
  int r = rem / (OUTCn * 32);
  int rem2 = rem - r * (OUTCn * 32);
  int o = rem2 >> 5;
  int cl = rem2 & 31;
  int c = ck * 32 + cl;
  float v = (c < CHn) ? W[((size_t)o * CHn + c) * 9 + r] : 0.f;
  Wt2[idx] = (short)f2bf(v);
}

// ---------------- Kernel P: coalesced pool gather (slim blocks) ----------------
// grid (28, 512): block = (8-channel chunk, batch). 256 thr, 23.3 KB LDS.
__global__ __launch_bounds__(256) void pool_kernel(const float* __restrict__ x,
                                                   const short* __restrict__ Mws,
                                                   const int* __restrict__ num1_ws,
                                                   short* __restrict__ Pool_ws) {
  __shared__ float xs[8 * Nn];    // 23,328 B
  const int ck8 = blockIdx.x;     // 0..27 -> channels [8*ck8, 8*ck8+8)
  const int b = blockIdx.y;
  const int tid = threadIdx.x;
  const int c0 = ck8 * 8;
  const int num1 = num1_ws[b];
  const float* xp = x + ((size_t)b * Cn + c0) * Nn;

  for (int i = tid; i < 8 * Nn; i += 256) {
    int cl = i / Nn;
    xs[i] = (c0 + cl < CHn) ? xp[i] : 0.f;   // guard protects both value & OOB
  }
  __syncthreads();

  if (tid < POOLR) {
    int m = tid;
    bool valid = m < num1;
    int s = valid ? (int)Mws[(size_t)b * MCAP + m] : 0;
    s16x8 w8;
#pragma unroll
    for (int j = 0; j < 8; ++j) {
      float v = valid ? xs[j * Nn + s] : 0.f;
      w8[j] = (short)f2bf(v);
    }
    *(s16x8*)(Pool_ws + ((size_t)b * POOLR + m) * CHP + c0) = w8;
  }
}

// ---------------- Kernel U: U[b][r][slot][o] = sum_c W[r][o][c]*Pool[b][slot][c] ----------------
// grid (9, 512), 256 thr = 4 waves (wave = o-group of 16). No LDS.
__global__ __launch_bounds__(256) void u_kernel(const short* __restrict__ Wt2,
                                                const short* __restrict__ Pool_ws,
                                                short* __restrict__ U_ws) {
  const int r = blockIdx.x;       // 0..8
  const int b = blockIdx.y;
  const int tid = threadIdx.x;
  const int lane = tid & 63;
  const int ot = tid >> 6;        // o-group 0..3
  const int l16 = lane & 15;
  const int kg = lane >> 4;

  const short* wp = Wt2 + ((size_t)r * OUTCn + ot * 16 + l16) * 32 + kg * 8;
  s16x8 av[NCHUNK];
#pragma unroll
  for (int ck = 0; ck < NCHUNK; ++ck) av[ck] = *(const s16x8*)(wp + (size_t)ck * (9 * OUTCn * 32));

  const short* pp = Pool_ws + (size_t)b * (POOLR * CHP) + l16 * CHP + kg * 8;

  f32x4 acc[11];
#pragma unroll
  for (int nt = 0; nt < 11; ++nt) {
    f32x4 a = (f32x4){0.f, 0.f, 0.f, 0.f};
    const short* q = pp + nt * 16 * CHP;
#pragma unroll
    for (int ck = 0; ck < NCHUNK; ++ck) {
      s16x8 bv = *(const s16x8*)(q + ck * 32);
      a = __builtin_amdgcn_mfma_f32_16x16x32_bf16(av[ck], bv, a, 0, 0, 0);
    }
    acc[nt] = a;
  }

  short* Ub = U_ws + (((size_t)b * 9 + r) * POOLR) * OUTCn;
#pragma unroll
  for (int nt = 0; nt < 11; ++nt) {
    int slot = nt * 16 + l16;                 // D col = l16
    s16x4 u4 = {(short)f2bf(acc[nt][0]), (short)f2bf(acc[nt][1]),
                (short)f2bf(acc[nt][2]), (short)f2bf(acc[nt][3])};
    *(s16x4*)(Ub + (size_t)slot * OUTCn + ot * 16 + kg * 4) = u4;   // D row = kg*4+q
  }
}

// ---------------- Kernel S: y[b][o][n] = bias[o] + sum_r U[b][r][slot_r(n)][o] ----------------
// grid (3, 512), 256 thr, no LDS, no barriers. thread = one pixel.
__global__ __launch_bounds__(256) void scatter_kernel(const short* __restrict__ U_ws,
                                                      const short* __restrict__ slotpad_ws,
                                                      const float* __restrict__ bias,
                                                      float* __restrict__ y) {
  const int bt = blockIdx.x;      // 0..2
  const int b = blockIdx.y;
  const int tid = threadIdx.x;
  if (tid >= 243) return;
  const int n = bt * 243 + tid;
  const int i = n / Pn, j = n - i * Pn;
  const short* sl = slotpad_ws + (size_t)b * SPAD + i * 29 + j;
  const short* Ub = U_ws + (size_t)b * 9 * POOLR * OUTCn;

  float acc[64];
#pragma unroll
  for (int k = 0; k < 64; ++k) acc[k] = 0.f;

#pragma unroll
  for (int r = 0; r < 9; ++r) {
    int slot = sl[(r / 3) * 29 + (r % 3)];
    const short* u = Ub + ((size_t)r * POOLR + slot) * OUTCn;
    s16x8 v[8];
#pragma unroll
    for (int s8 = 0; s8 < 8; ++s8) v[s8] = *(const s16x8*)(u + s8 * 8);
#pragma unroll
    for (int k = 0; k < 64; ++k) acc[k] += bf2f(v[k >> 3][k & 7]);
  }

  float* yb = y + (size_t)b * OUTCn * Nn + n;
#pragma unroll
  for (int o = 0; o < 64; ++o) {
    yb[(size_t)o * Nn] = acc[o] + bias[o];
  }
}

extern "C" void kernel_launch(void* const* d_in, const int* in_sizes, int n_in,
                              void* d_out, int out_size, void* d_ws, size_t ws_size,
                              hipStream_t stream) {
  const float* x = (const float*)d_in[0];
  const float* W = (const float*)d_in[1];
  const float* bias = (const float*)d_in[2];
  const int* rand_idx = (const int*)d_in[3];
  float* y = (float*)d_out;

  char* p = (char*)d_ws;
  short* slotpad = (short*)p;   p += 884736;      // 512*864*2
  short* Mws = (short*)p;       p += 196608;      // 512*192*2
  int* num1 = (int*)p;          p += 2048;
  short* Wt2 = (short*)p;       p += 258048;      // 7*9*64*32*2
  short* Pool_ws = (short*)p;   p += (size_t)Bn * POOLR * CHP * 2;   // 40,370,176 B
  short* U_ws = (short*)p;                                            // 512*9*176*64*2 = 103,809,024 B

  src_kernel<<<Bn, 256, 0, stream>>>(x, rand_idx, slotpad, Mws, num1);
  wprep_kernel<<<(NCHUNK * 9 * OUTCn * 32 + 255) / 256, 256, 0, stream>>>(W, Wt2);
  pool_kernel<<<dim3(28, Bn), 256, 0, stream>>>(x, Mws, num1, Pool_ws);
  u_kernel<<<dim3(9, Bn), 256, 0, stream>>>(Wt2, Pool_ws, U_ws);
  scatter_kernel<<<dim3(3, Bn), 256, 0, stream>>>(U_ws, slotpad, bias, y);
}

// Round 8
// 200.411 us; speedup vs baseline: 2.1585x; 2.0954x over previous
//
#include <hip/hip_runtime.h>

#define Bn 512
#define Cn 202
#define Pn 27
#define Nn 729
#define CHn 200
#define Kn 58
#define OUTCn 64
#define CENTERn 364    // 13*27+13
#define NCHUNK 7
#define POOLR 128      // pool rows (slots); row 127 always zero
#define ZSLOT 127
#define NCK8 28        // 8-channel chunks in padded 224 (25 real, 3 poison-but-A-zero)
#define MCAP 128
#define SPAD 864

typedef float f32x4 __attribute__((ext_vector_type(4)));
typedef f32x4 f32x4u __attribute__((aligned(4)));   // dword-aligned vector load
typedef short s16x8 __attribute__((ext_vector_type(8)));
typedef short s16x4 __attribute__((ext_vector_type(4)));

static __device__ __forceinline__ unsigned short f2bf(float f) {
  unsigned u = __float_as_uint(f);
  u += 0x7fffu + ((u >> 16) & 1u);   // RNE
  return (unsigned short)(u >> 16);
}
static __device__ __forceinline__ float bf2f(short s) {
  return __uint_as_float(((unsigned)(unsigned short)s) << 16);
}

// ---------------- Kernel A: slot table + masked-pool list (parallel scan) ----------------
__global__ __launch_bounds__(256) void src_kernel(const float* __restrict__ x,
                                                  const int* __restrict__ rand_idx,
                                                  short* __restrict__ slotpad_ws,
                                                  short* __restrict__ Mws,
                                                  int* __restrict__ num1_ws) {
  int b = blockIdx.x;
  __shared__ float sp[Nn];
  __shared__ short slotS[Nn];
  __shared__ short M[Nn];
  __shared__ int wsum[4];
  __shared__ int s_num;
  int tid = threadIdx.x;
  const int lane = tid & 63;
  const int wv = tid >> 6;
  const float* xsp = x + ((size_t)b * Cn + CHn) * Nn;
  for (int n = tid; n < Nn; n += 256) sp[n] = xsp[n];
  __syncthreads();
  float central = sp[CENTERn];
  __syncthreads();
  for (int k = tid; k < Kn; k += 256) sp[rand_idx[b * Kn + k]] = central;
  __syncthreads();

  // each thread owns 3 consecutive pixels
  int n0 = tid * 3;
  bool mk[3];
  int cnt = 0;
#pragma unroll
  for (int t = 0; t < 3; ++t) {
    int n = n0 + t;
    bool m = (n < Nn) && (sp[n] == central);
    mk[t] = m;
    cnt += m;
  }
  // wave inclusive scan
  int v = cnt;
#pragma unroll
  for (int off = 1; off < 64; off <<= 1) {
    int u = __shfl_up(v, off);
    if (lane >= off) v += u;
  }
  if (lane == 63) wsum[wv] = v;
  __syncthreads();
  if (tid == 0) {
    int s = 0;
#pragma unroll
    for (int w = 0; w < 4; ++w) { int t = wsum[w]; wsum[w] = s; s += t; }
    s_num = s;
  }
  __syncthreads();
  int num = s_num;                       // >= 1 (central always masked)
  int excl = v - cnt + wsum[wv];         // masked count before this thread's pixels
  int c = excl;
#pragma unroll
  for (int t = 0; t < 3; ++t) {
    int n = n0 + t;
    if (n < Nn) {
      if (mk[t]) { M[c] = (short)n; slotS[n] = (short)c; c++; }
      else { slotS[n] = (short)(~(n - c)); }   // zrank = n - (#masked before n)
    }
  }
  __syncthreads();

  int num1 = num < ZSLOT ? num : ZSLOT;  // pool rows actually filled
  if (tid == 0) num1_ws[b] = num1;
  for (int m = tid; m < MCAP; m += 256) Mws[(size_t)b * MCAP + m] = (m < num) ? M[m] : (short)0;
  for (int idx = tid; idx < 841; idx += 256) {
    int pi = idx / 29, pj = idx - pi * 29;
    short val = (short)ZSLOT;
    if (pi >= 1 && pi <= 27 && pj >= 1 && pj <= 27) {
      int n = (pi - 1) * Pn + (pj - 1);
      int s0 = slotS[n];
      int sv = (s0 >= 0) ? s0 : ((~s0) % num);
      if (sv > ZSLOT - 1) sv = ZSLOT - 1;   // freak-case clamp (num>127 is +6 sigma)
      val = (short)sv;
    }
    slotpad_ws[(size_t)b * SPAD + idx] = val;
  }
}

// ---------------- Kernel B: weights -> bf16, chunked layout Wt2[ck][r][o][32] ----------------
__global__ __launch_bounds__(256) void wprep_kernel(const float* __restrict__ W,
                                                    short* __restrict__ Wt2) {
  int idx = blockIdx.x * 256 + threadIdx.x;
  if (idx >= NCHUNK * 9 * OUTCn * 32) return;
  int ck = idx / (9 * OUTCn * 32);
  int rem = idx - ck * (9 * OUTCn * 32);
  int r = rem / (OUTCn * 32);
  int rem2 = rem - r * (OUTCn * 32);
  int o = rem2 >> 5;
  int cl = rem2 & 31;
  int cc = ck * 32 + cl;
  float v = (cc < CHn) ? W[((size_t)o * CHn + cc) * 9 + r] : 0.f;
  Wt2[idx] = (short)f2bf(v);
}

// ---------------- Kernel P: pool gather. grid (25, 512), vectorized + coalesced ----------------
// Pool layout: [b][28][128][8] bf16 (chunk-major). Chunks 25..27 unwritten (A-side weights are 0).
__global__ __launch_bounds__(256) void pool_kernel(const float* __restrict__ x,
                                                   const short* __restrict__ Mws,
                                                   const int* __restrict__ num1_ws,
                                                   short* __restrict__ Pool_ws) {
  __shared__ __align__(16) float xs[8 * Nn];   // 23,328 B
  const int ck8 = blockIdx.x;     // 0..24 -> channels [8*ck8, 8*ck8+8), all < 200
  const int b = blockIdx.y;
  const int tid = threadIdx.x;
  const int c0 = ck8 * 8;
  const float* xp = x + ((size_t)b * Cn + c0) * Nn;

  // vectorized coalesced stage: 1458 x 16B
  const f32x4u* xp4 = (const f32x4u*)xp;
  f32x4* xs4 = (f32x4*)xs;
  for (int v = tid; v < (8 * Nn) / 4; v += 256) xs4[v] = xp4[v];
  __syncthreads();

  if (tid < POOLR) {
    const int m = tid;
    const int num1 = num1_ws[b];
    bool valid = m < num1;
    int s = valid ? (int)Mws[(size_t)b * MCAP + m] : 0;
    s16x8 w8;
#pragma unroll
    for (int j = 0; j < 8; ++j) {
      float v = valid ? xs[j * Nn + s] : 0.f;
      w8[j] = (short)f2bf(v);
    }
    // lanes m consecutive -> fully contiguous 1KB/wave store
    *(s16x8*)(Pool_ws + ((size_t)b * NCK8 + ck8) * (POOLR * 8) + m * 8) = w8;
  }
}

// ---------------- Kernel U: U[b][r][slot][o] = sum_c W[r][o][c]*Pool[b][slot][c] ----------------
// grid (9, 512), 256 thr = 4 waves (wave = o-group ot). LDS transpose -> coalesced U writes.
__global__ __launch_bounds__(256) void u_kernel(const short* __restrict__ Wt2,
                                                const short* __restrict__ Pool_ws,
                                                short* __restrict__ U_ws) {
  __shared__ __align__(16) short Ulds[POOLR * 72];   // 18,432 B (pad 72 shorts/row)
  const int r = blockIdx.x;       // 0..8
  const int b = blockIdx.y;
  const int tid = threadIdx.x;
  const int lane = tid & 63;
  const int ot = tid >> 6;        // 0..3
  const int l16 = lane & 15;
  const int kg = lane >> 4;

  const short* wp = Wt2 + ((size_t)r * OUTCn + ot * 16 + l16) * 32 + kg * 8;
  s16x8 av[NCHUNK];
#pragma unroll
  for (int ck = 0; ck < NCHUNK; ++ck) av[ck] = *(const s16x8*)(wp + (size_t)ck * (9 * OUTCn * 32));

  const short* poolb = Pool_ws + (size_t)b * (NCK8 * POOLR * 8);

#pragma unroll
  for (int nt = 0; nt < 8; ++nt) {
    f32x4 a = (f32x4){0.f, 0.f, 0.f, 0.f};
#pragma unroll
    for (int ck = 0; ck < NCHUNK; ++ck) {
      int chunk8 = ck * 4 + kg;
      s16x8 bv = *(const s16x8*)(poolb + ((size_t)chunk8 * POOLR + nt * 16 + l16) * 8);
      a = __builtin_amdgcn_mfma_f32_16x16x32_bf16(av[ck], bv, a, 0, 0, 0);
    }
    // D: col(slot)=l16, row(o_local)=kg*4+q -> LDS [slot][o]
    s16x4 u4 = {(short)f2bf(a[0]), (short)f2bf(a[1]), (short)f2bf(a[2]), (short)f2bf(a[3])};
    *(s16x4*)(Ulds + (nt * 16 + l16) * 72 + ot * 16 + kg * 4) = u4;
  }
  __syncthreads();

  // coalesced write-out: 128 rows x 128 B
  short* Ub = U_ws + ((size_t)b * 9 + r) * (POOLR * OUTCn);
  for (int v = tid; v < POOLR * 8; v += 256) {
    int slot = v >> 3, seg = v & 7;
    *(s16x8*)(Ub + v * 8) = *(const s16x8*)(Ulds + slot * 72 + seg * 8);
  }
}

// ---------------- Kernel S: y[b][o][n] = bias[o] + sum_r U[b][r][slot_r(n)][o] ----------------
__global__ __launch_bounds__(256) void scatter_kernel(const short* __restrict__ U_ws,
                                                      const short* __restrict__ slotpad_ws,
                                                      const float* __restrict__ bias,
                                                      float* __restrict__ y) {
  __shared__ short Slot[841];
  const int bt = blockIdx.x;      // 0..2
  const int b = blockIdx.y;
  const int tid = threadIdx.x;
  for (int i = tid; i < 841; i += 256) Slot[i] = slotpad_ws[(size_t)b * SPAD + i];
  __syncthreads();
  if (tid >= 243) return;
  const int n = bt * 243 + tid;
  const int i = n / Pn, j = n - i * Pn;
  const int base = i * 29 + j;
  const short* Ub = U_ws + (size_t)b * 9 * POOLR * OUTCn;

  float acc[64];
#pragma unroll
  for (int k = 0; k < 64; ++k) acc[k] = 0.f;

#pragma unroll
  for (int r = 0; r < 9; ++r) {
    int slot = Slot[base + (r / 3) * 29 + (r % 3)];
    const short* u = Ub + ((size_t)r * POOLR + slot) * OUTCn;
    s16x8 v[8];
#pragma unroll
    for (int s8 = 0; s8 < 8; ++s8) v[s8] = *(const s16x8*)(u + s8 * 8);
#pragma unroll
    for (int k = 0; k < 64; ++k) acc[k] += bf2f(v[k >> 3][k & 7]);
  }

  float* yb = y + (size_t)b * OUTCn * Nn + n;
#pragma unroll
  for (int o = 0; o < 64; ++o) {
    yb[(size_t)o * Nn] = acc[o] + bias[o];
  }
}

extern "C" void kernel_launch(void* const* d_in, const int* in_sizes, int n_in,
                              void* d_out, int out_size, void* d_ws, size_t ws_size,
                              hipStream_t stream) {
  const float* x = (const float*)d_in[0];
  const float* W = (const float*)d_in[1];
  const float* bias = (const float*)d_in[2];
  const int* rand_idx = (const int*)d_in[3];
  float* y = (float*)d_out;

  char* p = (char*)d_ws;
  short* slotpad = (short*)p;   p += (size_t)Bn * SPAD * 2;            //    884,736
  short* Mws = (short*)p;       p += (size_t)Bn * MCAP * 2;            //    131,072
  int* num1 = (int*)p;          p += 2048;
  short* Wt2 = (short*)p;       p += (size_t)NCHUNK * 9 * OUTCn * 32 * 2; // 258,048
  short* Pool_ws = (short*)p;   p += (size_t)Bn * NCK8 * POOLR * 8 * 2;   // 29,360,128
  short* U_ws = (short*)p;                                                // 75,497,472

  src_kernel<<<Bn, 256, 0, stream>>>(x, rand_idx, slotpad, Mws, num1);
  wprep_kernel<<<(NCHUNK * 9 * OUTCn * 32 + 255) / 256, 256, 0, stream>>>(W, Wt2);
  pool_kernel<<<dim3(25, Bn), 256, 0, stream>>>(x, Mws, num1, Pool_ws);
  u_kernel<<<dim3(9, Bn), 256, 0, stream>>>(Wt2, Pool_ws, U_ws);
  scatter_kernel<<<dim3(3, Bn), 256, 0, stream>>>(U_ws, slotpad, bias, y);
}

// Round 9
// 185.924 us; speedup vs baseline: 2.3267x; 1.0779x over previous
//
#include <hip/hip_runtime.h>

#define Bn 512
#define Cn 202
#define Pn 27
#define Nn 729
#define CHn 200
#define Kn 58
#define OUTCn 64
#define CENTERn 364    // 13*27+13
#define NCHUNK 7
#define POOLR 128      // pool rows (slots); row 127 always zero
#define ZSLOT 127
#define NCK8 28        // 8-channel chunks in padded 224 (25 real, 3 poison-but-A-zero)
#define MCAP 128
#define SPAD 864
#define WTOT (NCHUNK * 9 * OUTCn * 32)   // 129024 = 512 * 252

typedef float f32x4 __attribute__((ext_vector_type(4)));
typedef f32x4 f32x4u __attribute__((aligned(4)));   // dword-aligned vector load
typedef short s16x8 __attribute__((ext_vector_type(8)));
typedef short s16x4 __attribute__((ext_vector_type(4)));

static __device__ __forceinline__ unsigned short f2bf(float f) {
  unsigned u = __float_as_uint(f);
  u += 0x7fffu + ((u >> 16) & 1u);   // RNE
  return (unsigned short)(u >> 16);
}
static __device__ __forceinline__ float bf2f(short s) {
  return __uint_as_float(((unsigned)(unsigned short)s) << 16);
}

// ---------------- Kernel A: slot table + masked-pool list (parallel scan) + weight prep ----------------
__global__ __launch_bounds__(256) void src_kernel(const float* __restrict__ x,
                                                  const int* __restrict__ rand_idx,
                                                  const float* __restrict__ W,
                                                  short* __restrict__ slotpad_ws,
                                                  short* __restrict__ Mws,
                                                  int* __restrict__ num1_ws,
                                                  short* __restrict__ Wt2) {
  int b = blockIdx.x;
  __shared__ float sp[Nn];
  __shared__ short slotS[Nn];
  __shared__ short M[Nn];
  __shared__ int wsum[4];
  __shared__ int s_num;
  int tid = threadIdx.x;
  const int lane = tid & 63;
  const int wv = tid >> 6;
  const float* xsp = x + ((size_t)b * Cn + CHn) * Nn;
  for (int n = tid; n < Nn; n += 256) sp[n] = xsp[n];
  __syncthreads();
  float central = sp[CENTERn];
  __syncthreads();
  for (int k = tid; k < Kn; k += 256) sp[rand_idx[b * Kn + k]] = central;
  __syncthreads();

  // each thread owns 3 consecutive pixels
  int n0 = tid * 3;
  bool mk[3];
  int cnt = 0;
#pragma unroll
  for (int t = 0; t < 3; ++t) {
    int n = n0 + t;
    bool m = (n < Nn) && (sp[n] == central);
    mk[t] = m;
    cnt += m;
  }
  // wave inclusive scan
  int v = cnt;
#pragma unroll
  for (int off = 1; off < 64; off <<= 1) {
    int u = __shfl_up(v, off);
    if (lane >= off) v += u;
  }
  if (lane == 63) wsum[wv] = v;
  __syncthreads();
  if (tid == 0) {
    int s = 0;
#pragma unroll
    for (int w = 0; w < 4; ++w) { int t = wsum[w]; wsum[w] = s; s += t; }
    s_num = s;
  }
  __syncthreads();
  int num = s_num;                       // >= 1 (central always masked)
  int excl = v - cnt + wsum[wv];         // masked count before this thread's pixels
  int c = excl;
#pragma unroll
  for (int t = 0; t < 3; ++t) {
    int n = n0 + t;
    if (n < Nn) {
      if (mk[t]) { M[c] = (short)n; slotS[n] = (short)c; c++; }
      else { slotS[n] = (short)(~(n - c)); }   // zrank = n - (#masked before n)
    }
  }
  __syncthreads();

  int num1 = num < ZSLOT ? num : ZSLOT;  // pool rows actually filled
  if (tid == 0) num1_ws[b] = num1;
  for (int m = tid; m < MCAP; m += 256) Mws[(size_t)b * MCAP + m] = (m < num) ? M[m] : (short)0;
  for (int idx = tid; idx < 841; idx += 256) {
    int pi = idx / 29, pj = idx - pi * 29;
    short val = (short)ZSLOT;
    if (pi >= 1 && pi <= 27 && pj >= 1 && pj <= 27) {
      int n = (pi - 1) * Pn + (pj - 1);
      int s0 = slotS[n];
      int sv = (s0 >= 0) ? s0 : ((~s0) % num);
      if (sv > ZSLOT - 1) sv = ZSLOT - 1;   // freak-case clamp (num>127 is +6 sigma)
      val = (short)sv;
    }
    slotpad_ws[(size_t)b * SPAD + idx] = val;
  }

  // ---- merged weight prep: block b converts elements [252b, 252b+252) of Wt2[ck][r][o][32]
  {
    int base = b * 252;
    if (tid < 252) {
      int idx = base + tid;
      int ck = idx / (9 * OUTCn * 32);
      int rem = idx - ck * (9 * OUTCn * 32);
      int r = rem / (OUTCn * 32);
      int rem2 = rem - r * (OUTCn * 32);
      int o = rem2 >> 5;
      int cl = rem2 & 31;
      int cc = ck * 32 + cl;
      float wval = (cc < CHn) ? W[((size_t)o * CHn + cc) * 9 + r] : 0.f;
      Wt2[idx] = (short)f2bf(wval);
    }
  }
}

// ---------------- Kernel P: pool gather. grid (25, 512), vectorized + coalesced ----------------
// Pool layout: [b][28][128][8] bf16 (chunk-major). Chunks 25..27 unwritten (A-side weights are 0).
__global__ __launch_bounds__(256) void pool_kernel(const float* __restrict__ x,
                                                   const short* __restrict__ Mws,
                                                   const int* __restrict__ num1_ws,
                                                   short* __restrict__ Pool_ws) {
  __shared__ __align__(16) float xs[8 * Nn];   // 23,328 B
  const int ck8 = blockIdx.x;     // 0..24 -> channels [8*ck8, 8*ck8+8), all < 200
  const int b = blockIdx.y;
  const int tid = threadIdx.x;
  const int c0 = ck8 * 8;
  const float* xp = x + ((size_t)b * Cn + c0) * Nn;

  // vectorized coalesced stage: 1458 x 16B (4B-aligned source)
  const f32x4u* xp4 = (const f32x4u*)xp;
  f32x4* xs4 = (f32x4*)xs;
  for (int v = tid; v < (8 * Nn) / 4; v += 256) xs4[v] = xp4[v];
  __syncthreads();

  if (tid < POOLR) {
    const int m = tid;
    const int num1 = num1_ws[b];
    bool valid = m < num1;
    int s = valid ? (int)Mws[(size_t)b * MCAP + m] : 0;
    s16x8 w8;
#pragma unroll
    for (int j = 0; j < 8; ++j) {
      float v = valid ? xs[j * Nn + s] : 0.f;
      w8[j] = (short)f2bf(v);
    }
    // lanes m consecutive -> fully contiguous 1KB/wave store
    *(s16x8*)(Pool_ws + ((size_t)b * NCK8 + ck8) * (POOLR * 8) + m * 8) = w8;
  }
}

// ---------------- Kernel U: U[b][r][slot][o] = sum_c W[r][o][c]*Pool[b][slot][c] ----------------
// grid (9, 512), 256 thr = 4 waves (wave = o-group ot). LDS transpose -> coalesced U writes.
__global__ __launch_bounds__(256) void u_kernel(const short* __restrict__ Wt2,
                                                const short* __restrict__ Pool_ws,
                                                short* __restrict__ U_ws) {
  __shared__ __align__(16) short Ulds[POOLR * 72];   // 18,432 B (pad 72 shorts/row)
  const int r = blockIdx.x;       // 0..8
  const int b = blockIdx.y;
  const int tid = threadIdx.x;
  const int lane = tid & 63;
  const int ot = tid >> 6;        // 0..3
  const int l16 = lane & 15;
  const int kg = lane >> 4;

  const short* wp = Wt2 + ((size_t)r * OUTCn + ot * 16 + l16) * 32 + kg * 8;
  s16x8 av[NCHUNK];
#pragma unroll
  for (int ck = 0; ck < NCHUNK; ++ck) av[ck] = *(const s16x8*)(wp + (size_t)ck * (9 * OUTCn * 32));

  const short* poolb = Pool_ws + (size_t)b * (NCK8 * POOLR * 8);

#pragma unroll
  for (int nt = 0; nt < 8; ++nt) {
    f32x4 a = (f32x4){0.f, 0.f, 0.f, 0.f};
#pragma unroll
    for (int ck = 0; ck < NCHUNK; ++ck) {
      int chunk8 = ck * 4 + kg;
      s16x8 bv = *(const s16x8*)(poolb + ((size_t)chunk8 * POOLR + nt * 16 + l16) * 8);
      a = __builtin_amdgcn_mfma_f32_16x16x32_bf16(av[ck], bv, a, 0, 0, 0);
    }
    // D: col(slot)=l16, row(o_local)=kg*4+q -> LDS [slot][o]
    s16x4 u4 = {(short)f2bf(a[0]), (short)f2bf(a[1]), (short)f2bf(a[2]), (short)f2bf(a[3])};
    *(s16x4*)(Ulds + (nt * 16 + l16) * 72 + ot * 16 + kg * 4) = u4;
  }
  __syncthreads();

  // coalesced write-out: 128 rows x 128 B
  short* Ub = U_ws + ((size_t)b * 9 + r) * (POOLR * OUTCn);
  for (int v = tid; v < POOLR * 8; v += 256) {
    int slot = v >> 3, seg = v & 7;
    *(s16x8*)(Ub + v * 8) = *(const s16x8*)(Ulds + slot * 72 + seg * 8);
  }
}

// ---------------- Kernel S: y[b][o][n] = bias[o] + sum_r U[b][r][slot_r(n)][o] ----------------
// grid (3, 512), 256 thr. Per r: coalesced 16KB U stage into padded LDS, slot-indexed b128 reads.
__global__ __launch_bounds__(256) void scatter_kernel(const short* __restrict__ U_ws,
                                                      const short* __restrict__ slotpad_ws,
                                                      const float* __restrict__ bias,
                                                      float* __restrict__ y) {
  __shared__ short Slot[841];
  __shared__ __align__(16) short Ulds[POOLR * 72];   // 18,432 B (144 B row stride)
  const int bt = blockIdx.x;      // 0..2
  const int b = blockIdx.y;
  const int tid = threadIdx.x;
  for (int i2 = tid; i2 < 841; i2 += 256) Slot[i2] = slotpad_ws[(size_t)b * SPAD + i2];

  const bool act = tid < 243;
  const int n = bt * 243 + (act ? tid : 0);
  const int pi = n / Pn, pj = n - pi * Pn;
  const int base = pi * 29 + pj;

  float acc[64];
#pragma unroll
  for (int k = 0; k < 64; ++k) acc[k] = 0.f;

  const short* Ub = U_ws + (size_t)b * 9 * POOLR * OUTCn;

  for (int r = 0; r < 9; ++r) {
    __syncthreads();   // previous r's LDS reads done (also orders Slot at r=0)
    const s16x8* srcv = (const s16x8*)(Ub + (size_t)r * (POOLR * OUTCn));
    for (int v = tid; v < POOLR * 8; v += 256) {
      *(s16x8*)(Ulds + (v >> 3) * 72 + (v & 7) * 8) = srcv[v];
    }
    __syncthreads();
    const int slot = Slot[base + (r / 3) * 29 + (r % 3)];
    const short* u = Ulds + slot * 72;
    s16x8 v[8];
#pragma unroll
    for (int s8 = 0; s8 < 8; ++s8) v[s8] = *(const s16x8*)(u + s8 * 8);
#pragma unroll
    for (int k = 0; k < 64; ++k) acc[k] += bf2f(v[k >> 3][k & 7]);
  }

  if (act) {
    float* yb = y + (size_t)b * OUTCn * Nn + n;
#pragma unroll
    for (int o = 0; o < 64; ++o) {
      yb[(size_t)o * Nn] = acc[o] + bias[o];
    }
  }
}

extern "C" void kernel_launch(void* const* d_in, const int* in_sizes, int n_in,
                              void* d_out, int out_size, void* d_ws, size_t ws_size,
                              hipStream_t stream) {
  const float* x = (const float*)d_in[0];
  const float* W = (const float*)d_in[1];
  const float* bias = (const float*)d_in[2];
  const int* rand_idx = (const int*)d_in[3];
  float* y = (float*)d_out;

  char* p = (char*)d_ws;
  short* slotpad = (short*)p;   p += (size_t)Bn * SPAD * 2;               //    884,736
  short* Mws = (short*)p;       p += (size_t)Bn * MCAP * 2;               //    131,072
  int* num1 = (int*)p;          p += 2048;
  short* Wt2 = (short*)p;       p += (size_t)WTOT * 2;                    //    258,048
  short* Pool_ws = (short*)p;   p += (size_t)Bn * NCK8 * POOLR * 8 * 2;   // 29,360,128
  short* U_ws = (short*)p;                                                 // 75,497,472

  src_kernel<<<Bn, 256, 0, stream>>>(x, rand_idx, W, slotpad, Mws, num1, Wt2);
  pool_kernel<<<dim3(25, Bn), 256, 0, stream>>>(x, Mws, num1, Pool_ws);
  u_kernel<<<dim3(9, Bn), 256, 0, stream>>>(Wt2, Pool_ws, U_ws);
  scatter_kernel<<<dim3(3, Bn), 256, 0, stream>>>(U_ws, slotpad, bias, y);
}